// Round 5
// baseline (182.658 us; speedup 1.0000x reference)
//
#include <hip/hip_runtime.h>

#define T_LEN 2048
#define B_SZ  2048
#define H_SZ  8
#define SKEW  5       // ticks of layer skew = import slots + 1
#define WARM  20      // layer l live from tick 5l; outputs from tick 20
#define XS_N  2080    // xs zero-padded; reads up to xs[2075]

__global__ __launch_bounds__(64, 1)
void rnn_fasm(const float* __restrict__ x,
              const float* __restrict__ h0_in,
              const float* __restrict__ w_ih0,
              const float* __restrict__ w_ih,
              const float* __restrict__ w_hh,
              const float* __restrict__ b_ih,
              const float* __restrict__ b_hh,
              const float* __restrict__ w_lin,
              const float* __restrict__ b_lin,
              float* __restrict__ out)
{
    __shared__ __align__(16) float xs[XS_N];

    const int lane = threadIdx.x;
    const int u    = lane & 7;            // hidden unit
    const int l    = lane >> 4;           // row = layer
    const bool grB = ((lane >> 3) & 1);   // A-half: own dot (+base), B-half: export dot
    const int lp   = (l + 3) & 3;         // import source row (row0 <- row3 = output)
    const int bidx = (((lp << 4) | 8 | u)) << 2;   // pull from source row's B-half

    for (int i = lane; i < XS_N; i += 64) xs[i] = 0.0f;
    __syncthreads();
    for (int i = lane; i < T_LEN; i += 64) xs[i] = x[(size_t)i * B_SZ + (B_SZ - 1)];
    __syncthreads();

    // DPP direction probe (HW-verified); asm row_ror:s == ctrl 0x120+s
    int rot1 = __builtin_amdgcn_update_dpp(0, lane, 0x121, 0xF, 0xF, false);
    const bool plus = ((rot1 & 15) == ((lane + 1) & 15));

    const float C   = 2.0f * 1.4426950408889634f;  // h=tanh(a) -> r=rcp(exp2(C*a)+1)
    const float m2C = -2.0f * C;

    float whh_rs = 0.0f, wih_rs = 0.0f, wlin_rs = 0.0f;
    #pragma unroll
    for (int j = 0; j < 8; ++j) {
        whh_rs += w_hh[(l * H_SZ + u) * H_SZ + j];
        if (l > 0) wih_rs += w_ih[((l - 1) * H_SZ + u) * H_SZ + j];
        wlin_rs += w_lin[j];
    }
    const float bl_tot = wlin_rs + b_lin[0];

    // per-lane dot weights: A-half = own recurrence (-2C*whh), B-half = export
    float wsel[8];
    #pragma unroll
    for (int s = 0; s < 8; ++s) {
        int j = plus ? ((u + s) & 7) : ((u - s) & 7);
        float whh2  = m2C * w_hh[(l * H_SZ + u) * H_SZ + j];
        float wexp2 = (l < 3) ? m2C * w_ih[(l * H_SZ + u) * H_SZ + j]
                              : -2.0f * w_lin[j];
        wsel[s] = grB ? wexp2 : whh2;
    }
    const float tbase = (grB && l == 3) ? bl_tot : 0.0f;   // output bias on row-3 export
    const float xconst_a = C * (b_ih[l * H_SZ + u] + b_hh[l * H_SZ + u]
                                + whh_rs + ((l > 0) ? wih_rs : 0.0f));
    // dual-duty constants: A-half -> base terms, B-half -> tbase (no cndmask in loop)
    const float wx2p    = (!grB && l == 0) ? C * w_ih0[u] : 0.0f;
    const float xconstp = grB ? tbase : xconst_a;
    const float selp    = (grB || l == 0) ? 0.0f : 1.0f;   // row0 import = OUTPUT, not y-term

    // state r = (1 - h)/2
    float r = __builtin_fmaf(-0.5f, h0_in[((size_t)l * B_SZ + (B_SZ - 1)) * H_SZ + u], 0.5f);

    // 4-deep import pipeline: bpermute issued at tick k lands in ip[k%4],
    // consumed after tick k+3 (~3 asm blocks of slack) -> DS latency hidden.
    float ip0 = 0.0f, ip1 = 0.0f, ip2 = 0.0f, ip3 = 0.0f;

    // Tick, chain-optimized (round 4):
    //  - A-half critical cycle: dot(2x4 FMA chains) -> add S -> exp -> add 1.0
    //    -> rcp.  The old e-broadcast (exp->DPP detour, ~6 cyc) is GONE from
    //    this path: B-half now computes garbage through add/rcp (finite, no
    //    traps) and receives A's rn via bank-masked ror8 AFTER rcp, inside
    //    rcp's dep shadow (next tick's first FMA waits on rcp anyway).
    //  - fma t + s_nop 0 = 2 wait states for exp->add (trans->VALU, safe);
    //    s_nop 1 = 2 wait states for rcp->DPP (HW rule).
    //  - B's r is a copy of A's rn: bit-identical to the old recompute.
    auto tick = [&](float& ip_slot, float base, float xv_next, float& t_out) -> float {
        float c0 = base, c1, S, e, t, rn;
        asm("v_fma_f32      %[c0], %[w0], %[r], %[c0]\n\t"
            "v_mul_f32_dpp  %[c1], %[r], %[w4] row_ror:4 row_mask:0xf bank_mask:0xf\n\t"
            "v_fmac_f32_dpp %[c0], %[r], %[w1] row_ror:1 row_mask:0xf bank_mask:0xf\n\t"
            "v_fmac_f32_dpp %[c1], %[r], %[w5] row_ror:5 row_mask:0xf bank_mask:0xf\n\t"
            "v_fmac_f32_dpp %[c0], %[r], %[w2] row_ror:2 row_mask:0xf bank_mask:0xf\n\t"
            "v_fmac_f32_dpp %[c1], %[r], %[w6] row_ror:6 row_mask:0xf bank_mask:0xf\n\t"
            "v_fmac_f32_dpp %[c0], %[r], %[w3] row_ror:3 row_mask:0xf bank_mask:0xf\n\t"
            "v_fmac_f32_dpp %[c1], %[r], %[w7] row_ror:7 row_mask:0xf bank_mask:0xf\n\t"
            "v_add_f32      %[S], %[c0], %[c1]\n\t"
            "v_exp_f32      %[e], %[S]\n\t"
            "v_fma_f32      %[t], %[wx], %[xv], %[xc]\n\t"
            "s_nop 0\n\t"
            "v_add_f32      %[e], 1.0, %[e]\n\t"
            "v_rcp_f32      %[rn], %[e]\n\t"
            "s_nop 1\n\t"
            "v_mov_b32_dpp  %[rn], %[rn] row_ror:8 row_mask:0xf bank_mask:0xc"
            : [c0]"+v"(c0), [c1]"=&v"(c1), [S]"=&v"(S), [e]"=&v"(e),
              [t]"=&v"(t), [rn]"=&v"(rn)
            : [r]"v"(r), [w0]"v"(wsel[0]), [w1]"v"(wsel[1]), [w2]"v"(wsel[2]),
              [w3]"v"(wsel[3]), [w4]"v"(wsel[4]), [w5]"v"(wsel[5]),
              [w6]"v"(wsel[6]), [w7]"v"(wsel[7]),
              [wx]"v"(wx2p), [xv]"v"(xv_next), [xc]"v"(xconstp));
        ip_slot = __int_as_float(__builtin_amdgcn_ds_bpermute(bidx, __float_as_int(S)));
        t_out = t;
        return rn;
    };

    // ---- warm-up ticks 0..19: layer l's r updates only from tick 5l ----
    float baseA = __builtin_fmaf(wx2p, xs[0], xconstp);  // tick 0 base (ip=0)
    float baseB = 0.0f;                                  // set before first use
    #pragma unroll
    for (int k = 0; k < WARM; ++k) {
        float rn, t;
        if      ((k & 3) == 0) { rn = tick(ip0, baseA, xs[k + 1], t); baseB = __builtin_fmaf(selp, ip1, t); }
        else if ((k & 3) == 1) { rn = tick(ip1, baseB, xs[k + 1], t); baseA = __builtin_fmaf(selp, ip2, t); }
        else if ((k & 3) == 2) { rn = tick(ip2, baseA, xs[k + 1], t); baseB = __builtin_fmaf(selp, ip3, t); }
        else                   { rn = tick(ip3, baseB, xs[k + 1], t); baseA = __builtin_fmaf(selp, ip0, t); }
        r = (k >= SKEW * l) ? rn : r;
    }
    float ov_carry = ip0;   // written at tick 16 -> out[0] (row0)

    // ---- main: ticks 20..2067, 8 per iteration; tick k emits out[k-20] ----
    const float4* xsv = (const float4*)xs;
    float4 xq  = xsv[5];   // xs[20..23]
    float4 xq2 = xsv[6];   // xs[24..27]
    for (int kb = WARM; kb <= 2060; kb += 8) {
        float4 xn1 = xsv[(kb >> 2) + 2];   // xs[kb+8 .. kb+11]
        float4 xn2 = xsv[(kb >> 2) + 3];   // xs[kb+12 .. kb+15]
        float o0 = ov_carry, o1, o2, o3, o4, o5, o6, o7, t;
        r = tick(ip0, baseA, xq.y,  t); o1 = ip1; baseB = __builtin_fmaf(selp, ip1, t);
        r = tick(ip1, baseB, xq.z,  t); o2 = ip2; baseA = __builtin_fmaf(selp, ip2, t);
        r = tick(ip2, baseA, xq.w,  t); o3 = ip3; baseB = __builtin_fmaf(selp, ip3, t);
        r = tick(ip3, baseB, xq2.x, t); o4 = ip0; baseA = __builtin_fmaf(selp, ip0, t);
        r = tick(ip0, baseA, xq2.y, t); o5 = ip1; baseB = __builtin_fmaf(selp, ip1, t);
        r = tick(ip1, baseB, xq2.z, t); o6 = ip2; baseA = __builtin_fmaf(selp, ip2, t);
        r = tick(ip2, baseA, xq2.w, t); o7 = ip3; baseB = __builtin_fmaf(selp, ip3, t);
        r = tick(ip3, baseB, xn1.x, t); ov_carry = ip0; baseA = __builtin_fmaf(selp, ip0, t);
        if (lane == 0) {
            *(float4*)(out + (kb - WARM))     = make_float4(o0, o1, o2, o3);
            *(float4*)(out + (kb - WARM) + 4) = make_float4(o4, o5, o6, o7);
        }
        xq = xn1; xq2 = xn2;
    }
}

extern "C" void kernel_launch(void* const* d_in, const int* in_sizes, int n_in,
                              void* d_out, int out_size, void* d_ws, size_t ws_size,
                              hipStream_t stream) {
    const float* x     = (const float*)d_in[0];
    const float* h0    = (const float*)d_in[1];
    const float* w_ih0 = (const float*)d_in[2];
    const float* w_ih  = (const float*)d_in[3];
    const float* w_hh  = (const float*)d_in[4];
    const float* b_ih  = (const float*)d_in[5];
    const float* b_hh  = (const float*)d_in[6];
    const float* w_lin = (const float*)d_in[7];
    const float* b_lin = (const float*)d_in[8];
    float* out = (float*)d_out;

    rnn_fasm<<<dim3(1), dim3(64), 0, stream>>>(
        x, h0, w_ih0, w_ih, w_hh, b_ih, b_hh, w_lin, b_lin, out);
}

// Round 6
// 173.138 us; speedup vs baseline: 1.0550x; 1.0550x over previous
//
#include <hip/hip_runtime.h>

#define T_LEN 2048
#define B_SZ  2048
#define H_SZ  8
#define SKEW  5       // ticks of layer skew = import slots + 1
#define WARM  20      // layer l live from tick 5l; outputs from tick 20
#define XS_N  2080    // xs zero-padded; reads up to xs[2075]

__global__ __launch_bounds__(64, 1)
void rnn_fasm(const float* __restrict__ x,
              const float* __restrict__ h0_in,
              const float* __restrict__ w_ih0,
              const float* __restrict__ w_ih,
              const float* __restrict__ w_hh,
              const float* __restrict__ b_ih,
              const float* __restrict__ b_hh,
              const float* __restrict__ w_lin,
              const float* __restrict__ b_lin,
              float* __restrict__ out)
{
    __shared__ __align__(16) float xs[XS_N];

    const int lane = threadIdx.x;
    const int u    = lane & 7;            // hidden unit
    const int l    = lane >> 4;           // row = layer
    const bool grB = ((lane >> 3) & 1);   // A-half: own dot (+base), B-half: export dot
    const int lp   = (l + 3) & 3;         // import source row (row0 <- row3 = output)
    const int bidx = (((lp << 4) | 8 | u)) << 2;   // pull from source row's B-half

    for (int i = lane; i < XS_N; i += 64) xs[i] = 0.0f;
    __syncthreads();
    for (int i = lane; i < T_LEN; i += 64) xs[i] = x[(size_t)i * B_SZ + (B_SZ - 1)];
    __syncthreads();

    // DPP direction probe (HW-verified); asm row_ror:s == ctrl 0x120+s
    int rot1 = __builtin_amdgcn_update_dpp(0, lane, 0x121, 0xF, 0xF, false);
    const bool plus = ((rot1 & 15) == ((lane + 1) & 15));

    const float C   = 2.0f * 1.4426950408889634f;  // h=tanh(a) -> r=rcp(exp2(C*a)+1)
    const float m2C = -2.0f * C;

    float whh_rs = 0.0f, wih_rs = 0.0f, wlin_rs = 0.0f;
    #pragma unroll
    for (int j = 0; j < 8; ++j) {
        whh_rs += w_hh[(l * H_SZ + u) * H_SZ + j];
        if (l > 0) wih_rs += w_ih[((l - 1) * H_SZ + u) * H_SZ + j];
        wlin_rs += w_lin[j];
    }
    const float bl_tot = wlin_rs + b_lin[0];

    // per-lane dot weights: A-half = own recurrence (-2C*whh), B-half = export
    float wsel[8];
    #pragma unroll
    for (int s = 0; s < 8; ++s) {
        int j = plus ? ((u + s) & 7) : ((u - s) & 7);
        float whh2  = m2C * w_hh[(l * H_SZ + u) * H_SZ + j];
        float wexp2 = (l < 3) ? m2C * w_ih[(l * H_SZ + u) * H_SZ + j]
                              : -2.0f * w_lin[j];
        wsel[s] = grB ? wexp2 : whh2;
    }
    const float tbase = (grB && l == 3) ? bl_tot : 0.0f;   // output bias on row-3 export
    const float xconst_a = C * (b_ih[l * H_SZ + u] + b_hh[l * H_SZ + u]
                                + whh_rs + ((l > 0) ? wih_rs : 0.0f));
    // dual-duty constants: A-half -> base terms, B-half -> tbase (no cndmask in loop)
    const float wx2p    = (!grB && l == 0) ? C * w_ih0[u] : 0.0f;
    const float xconstp = grB ? tbase : xconst_a;
    const float selp    = (grB || l == 0) ? 0.0f : 1.0f;   // row0 import = OUTPUT, not y-term

    // state r = (1 - h)/2
    float r = __builtin_fmaf(-0.5f, h0_in[((size_t)l * B_SZ + (B_SZ - 1)) * H_SZ + u], 0.5f);

    // 4-deep import pipeline: bpermute issued at tick k lands in ip[k%4],
    // consumed after tick k+3 (~3 asm blocks of slack) -> DS latency hidden.
    float ip0 = 0.0f, ip1 = 0.0f, ip2 = 0.0f, ip3 = 0.0f;

    // ---- warm-up tick: EXACT R1 schedule (known-correct hazard fill) ----
    auto tickW = [&](float& ip_slot, float base, float xv_next, float& t_out) -> float {
        float c0 = base, c1, S, e, t, rn;
        asm("s_nop 0\n\t"
            "v_fma_f32      %[c0], %[w0], %[r], %[c0]\n\t"
            "v_mul_f32_dpp  %[c1], %[r], %[w4] row_ror:4 row_mask:0xf bank_mask:0xf\n\t"
            "v_fmac_f32_dpp %[c0], %[r], %[w1] row_ror:1 row_mask:0xf bank_mask:0xf\n\t"
            "v_fmac_f32_dpp %[c1], %[r], %[w5] row_ror:5 row_mask:0xf bank_mask:0xf\n\t"
            "v_fmac_f32_dpp %[c0], %[r], %[w2] row_ror:2 row_mask:0xf bank_mask:0xf\n\t"
            "v_fmac_f32_dpp %[c1], %[r], %[w6] row_ror:6 row_mask:0xf bank_mask:0xf\n\t"
            "v_fmac_f32_dpp %[c0], %[r], %[w3] row_ror:3 row_mask:0xf bank_mask:0xf\n\t"
            "v_fmac_f32_dpp %[c1], %[r], %[w7] row_ror:7 row_mask:0xf bank_mask:0xf\n\t"
            "v_add_f32      %[S], %[c0], %[c1]\n\t"
            "v_exp_f32      %[e], %[S]\n\t"
            "v_fma_f32      %[t], %[wx], %[xv], %[xc]\n\t"
            "s_nop 0\n\t"
            "v_mov_b32_dpp  %[e], %[e] row_ror:8 row_mask:0xf bank_mask:0xc\n\t"
            "v_add_f32      %[e], 1.0, %[e]\n\t"
            "v_rcp_f32      %[rn], %[e]"
            : [c0]"+v"(c0), [c1]"=&v"(c1), [S]"=&v"(S), [e]"=&v"(e),
              [t]"=&v"(t), [rn]"=&v"(rn)
            : [r]"v"(r), [w0]"v"(wsel[0]), [w1]"v"(wsel[1]), [w2]"v"(wsel[2]),
              [w3]"v"(wsel[3]), [w4]"v"(wsel[4]), [w5]"v"(wsel[5]),
              [w6]"v"(wsel[6]), [w7]"v"(wsel[7]),
              [wx]"v"(wx2p), [xv]"v"(xv_next), [xc]"v"(xconstp));
        ip_slot = __int_as_float(__builtin_amdgcn_ds_bpermute(bidx, __float_as_int(S)));
        t_out = t;
        return rn;
    };

    // ---- main-loop tick (round 5): base-fma moved INTO the exp shadow ----
    //  - slot12 base-fma replaces the wasted s_nop as 2nd exp->DPP wait state
    //    AND pre-computes next tick's c0 operand -> rcp->dot gap shrinks to
    //    {bperm, o-mov, fma c0} (>=2 slots, rcp->DPP hazard satisfied).
    //  - no leading s_nop: externals + leading non-DPP fma provide separation.
    //  - arithmetic bit-identical to tickW.
    auto tickF = [&](float& ip_slot, float ipb, float base, float xv_next,
                     float& base_out) -> float {
        float c0 = base, c1, S, e, t, rn, bo;
        asm("v_fma_f32      %[c0], %[w0], %[r], %[c0]\n\t"
            "v_mul_f32_dpp  %[c1], %[r], %[w4] row_ror:4 row_mask:0xf bank_mask:0xf\n\t"
            "v_fmac_f32_dpp %[c0], %[r], %[w1] row_ror:1 row_mask:0xf bank_mask:0xf\n\t"
            "v_fmac_f32_dpp %[c1], %[r], %[w5] row_ror:5 row_mask:0xf bank_mask:0xf\n\t"
            "v_fmac_f32_dpp %[c0], %[r], %[w2] row_ror:2 row_mask:0xf bank_mask:0xf\n\t"
            "v_fmac_f32_dpp %[c1], %[r], %[w6] row_ror:6 row_mask:0xf bank_mask:0xf\n\t"
            "v_fmac_f32_dpp %[c0], %[r], %[w3] row_ror:3 row_mask:0xf bank_mask:0xf\n\t"
            "v_fmac_f32_dpp %[c1], %[r], %[w7] row_ror:7 row_mask:0xf bank_mask:0xf\n\t"
            "v_add_f32      %[S], %[c0], %[c1]\n\t"
            "v_exp_f32      %[e], %[S]\n\t"
            "v_fma_f32      %[t], %[wx], %[xv], %[xc]\n\t"
            "v_fma_f32      %[bo], %[sp], %[ipb], %[t]\n\t"
            "v_mov_b32_dpp  %[e], %[e] row_ror:8 row_mask:0xf bank_mask:0xc\n\t"
            "v_add_f32      %[e], 1.0, %[e]\n\t"
            "v_rcp_f32      %[rn], %[e]"
            : [c0]"+v"(c0), [c1]"=&v"(c1), [S]"=&v"(S), [e]"=&v"(e),
              [t]"=&v"(t), [rn]"=&v"(rn), [bo]"=&v"(bo)
            : [r]"v"(r), [w0]"v"(wsel[0]), [w1]"v"(wsel[1]), [w2]"v"(wsel[2]),
              [w3]"v"(wsel[3]), [w4]"v"(wsel[4]), [w5]"v"(wsel[5]),
              [w6]"v"(wsel[6]), [w7]"v"(wsel[7]),
              [wx]"v"(wx2p), [xv]"v"(xv_next), [xc]"v"(xconstp),
              [sp]"v"(selp), [ipb]"v"(ipb));
        ip_slot = __int_as_float(__builtin_amdgcn_ds_bpermute(bidx, __float_as_int(S)));
        base_out = bo;
        return rn;
    };

    // ---- warm-up ticks 0..19: layer l's r updates only from tick 5l ----
    float baseA = __builtin_fmaf(wx2p, xs[0], xconstp);  // tick 0 base (ip=0)
    float baseB = 0.0f;                                  // set before first use
    #pragma unroll
    for (int k = 0; k < WARM; ++k) {
        float rn, t;
        if      ((k & 3) == 0) { rn = tickW(ip0, baseA, xs[k + 1], t); baseB = __builtin_fmaf(selp, ip1, t); }
        else if ((k & 3) == 1) { rn = tickW(ip1, baseB, xs[k + 1], t); baseA = __builtin_fmaf(selp, ip2, t); }
        else if ((k & 3) == 2) { rn = tickW(ip2, baseA, xs[k + 1], t); baseB = __builtin_fmaf(selp, ip3, t); }
        else                   { rn = tickW(ip3, baseB, xs[k + 1], t); baseA = __builtin_fmaf(selp, ip0, t); }
        r = (k >= SKEW * l) ? rn : r;
    }
    float ov_carry = ip0;   // written at tick 16 -> out[0] (row0)

    // ---- main: ticks 20..2067, 8 per iteration; tick k emits out[k-20] ----
    const float4* xsv = (const float4*)xs;
    float4 xq  = xsv[5];   // xs[20..23]
    float4 xq2 = xsv[6];   // xs[24..27]
    for (int kb = WARM; kb <= 2060; kb += 8) {
        float4 xn1 = xsv[(kb >> 2) + 2];   // xs[kb+8 .. kb+11]
        float4 xn2 = xsv[(kb >> 2) + 3];   // xs[kb+12 .. kb+15]
        float o0 = ov_carry, o1, o2, o3, o4, o5, o6, o7;
        r = tickF(ip0, ip1, baseA, xq.y,  baseB); o1 = ip1;
        r = tickF(ip1, ip2, baseB, xq.z,  baseA); o2 = ip2;
        r = tickF(ip2, ip3, baseA, xq.w,  baseB); o3 = ip3;
        r = tickF(ip3, ip0, baseB, xq2.x, baseA); o4 = ip0;
        r = tickF(ip0, ip1, baseA, xq2.y, baseB); o5 = ip1;
        r = tickF(ip1, ip2, baseB, xq2.z, baseA); o6 = ip2;
        r = tickF(ip2, ip3, baseA, xq2.w, baseB); o7 = ip3;
        r = tickF(ip3, ip0, baseB, xn1.x, baseA); ov_carry = ip0;
        if (lane == 0) {
            *(float4*)(out + (kb - WARM))     = make_float4(o0, o1, o2, o3);
            *(float4*)(out + (kb - WARM) + 4) = make_float4(o4, o5, o6, o7);
        }
        xq = xn1; xq2 = xn2;
    }
}

extern "C" void kernel_launch(void* const* d_in, const int* in_sizes, int n_in,
                              void* d_out, int out_size, void* d_ws, size_t ws_size,
                              hipStream_t stream) {
    const float* x     = (const float*)d_in[0];
    const float* h0    = (const float*)d_in[1];
    const float* w_ih0 = (const float*)d_in[2];
    const float* w_ih  = (const float*)d_in[3];
    const float* w_hh  = (const float*)d_in[4];
    const float* b_ih  = (const float*)d_in[5];
    const float* b_hh  = (const float*)d_in[6];
    const float* w_lin = (const float*)d_in[7];
    const float* b_lin = (const float*)d_in[8];
    float* out = (float*)d_out;

    rnn_fasm<<<dim3(1), dim3(64), 0, stream>>>(
        x, h0, w_ih0, w_ih, w_hh, b_ih, b_hh, w_lin, b_lin, out);
}